// Round 1
// baseline (1083.852 us; speedup 1.0000x reference)
//
#include <hip/hip_runtime.h>
#include <math.h>
#include <float.h>

#define Hd 512
#define Wd 512
#define HWp (Hd*Wd)
#define Bn 16
#define Cn 3
#define NMAP (Bn*Cn)
#define KTOP 500
#define SLICES 32
#define ROWS_PER (Hd/SLICES)

__device__ __forceinline__ uint32_t flipbits(float v){
  uint32_t u = __float_as_uint(v);
  return u ^ (0x80000000u | (uint32_t)(-(int32_t)(u>>31)));
}
__device__ __forceinline__ float unflipbits(uint32_t f){
  uint32_t u = f ^ ((f>>31)? 0x80000000u : 0xFFFFFFFFu);
  return __uint_as_float(u);
}

// ---------------- Kernel 1: NMS (raw domain) + peak compaction ----------------
__global__ __launch_bounds__(256) void k_nms_compact(
    const float* __restrict__ hm, uint64_t* __restrict__ cand,
    uint32_t* __restrict__ cnt, int cap)
{
  int bc    = blockIdx.x / SLICES;
  int slice = blockIdx.x % SLICES;
  const float* map = hm + (size_t)bc * HWp;
  uint64_t* mycand = cand + (size_t)bc * (size_t)cap;
  int y0 = slice * ROWS_PER;
  int tid = threadIdx.x;
  int lane = tid & 63;
  const int QW = Wd / 4;                 // quads per row
  const int nquads = ROWS_PER * QW;      // 2048, divisible by 256 -> uniform trip count

  for (int q = tid; q < nquads; q += 256) {
    int y  = y0 + q / QW;
    int x4 = (q % QW) * 4;
    float e[3][6];
    bool rv[3];
    #pragma unroll
    for (int r = 0; r < 3; ++r) {
      int yy = y + r - 1;
      rv[r] = (yy >= 0 && yy < Hd);
      if (rv[r]) {
        const float* rw = map + (size_t)yy * Wd;
        float4 cc = *(const float4*)(rw + x4);
        e[r][0] = (x4 > 0)      ? rw[x4 - 1] : -INFINITY;
        e[r][1] = cc.x; e[r][2] = cc.y; e[r][3] = cc.z; e[r][4] = cc.w;
        e[r][5] = (x4 + 4 < Wd) ? rw[x4 + 4] : -INFINITY;
      } else {
        #pragma unroll
        for (int t = 0; t < 6; ++t) e[r][t] = -INFINITY;
      }
    }
    #pragma unroll
    for (int j = 0; j < 4; ++j) {
      float v = e[1][j + 1];
      bool peak =
        (v >= e[0][j]) && (v >= e[0][j+1]) && (v >= e[0][j+2]) &&
        (v >= e[1][j])                     && (v >= e[1][j+2]) &&
        (v >= e[2][j]) && (v >= e[2][j+1]) && (v >= e[2][j+2]);
      unsigned long long m = __ballot(peak);
      if (m) {
        int leader = __ffsll((long long)m) - 1;
        int tot = __popcll(m);
        int base = 0;
        if (lane == leader) base = (int)atomicAdd(&cnt[bc], (uint32_t)tot);
        base = __shfl(base, leader);
        if (peak) {
          uint32_t idx = (uint32_t)(y * Wd + x4 + j);
          uint64_t key = ((uint64_t)flipbits(v) << 32) | (uint32_t)(~idx);
          int my = __popcll(m & ((lane == 0) ? 0ull : ((~0ull) >> (64 - lane))));
          int p = base + my;
          if (p < cap) mycand[p] = key;
        }
      }
    }
  }
}

// ---------------- radix-select helper: find bin where cumsum-from-top crosses target
__device__ void findThreshold(uint32_t* hist, uint32_t* gsum, int target,
                              uint32_t* outBin, int* outKrem, int tid)
{
  uint32_t s = hist[4*tid] + hist[4*tid+1] + hist[4*tid+2] + hist[4*tid+3];
  gsum[tid] = s;
  __syncthreads();
  for (int d = 1; d < 1024; d <<= 1) {
    uint32_t v = (tid + d < 1024) ? gsum[tid + d] : 0u;
    __syncthreads();
    gsum[tid] += v;
    __syncthreads();
  }
  // gsum[t] = sum over groups >= t. Find largest t with gsum[t] >= target.
  if (gsum[tid] >= (uint32_t)target && (tid == 1023 || gsum[tid+1] < (uint32_t)target)) {
    uint32_t cum = (tid == 1023) ? 0u : gsum[tid+1];
    for (int b = 4*tid + 3; b >= 4*tid; --b) {
      cum += hist[b];
      if (cum >= (uint32_t)target) {
        *outBin  = (uint32_t)b;
        *outKrem = target - (int)(cum - hist[b]);
        break;
      }
    }
  }
  __syncthreads();
}

__device__ void bitonic2048_desc(uint64_t* a, int tid)
{
  for (int k = 2; k <= 2048; k <<= 1) {
    for (int j = k >> 1; j > 0; j >>= 1) {
      for (int i = tid; i < 2048; i += 1024) {
        int ixj = i ^ j;
        if (ixj > i) {
          uint64_t x = a[i], y = a[ixj];
          bool desc = ((i & k) == 0);
          if (desc ? (x < y) : (x > y)) { a[i] = y; a[ixj] = x; }
        }
      }
      __syncthreads();
    }
  }
}

// ---------------- Kernel 2: per-(b,c) top-500 via 2-level radix select + sort ----------------
__global__ __launch_bounds__(1024) void k_select(
    const uint64_t* __restrict__ cand, const uint32_t* __restrict__ cnt, int cap,
    float* __restrict__ s1_scores, uint32_t* __restrict__ s1_inds)
{
  __shared__ uint32_t hist[4096];
  __shared__ uint32_t gsum[1024];
  __shared__ uint64_t sbuf[2048];
  __shared__ uint32_t sh_T1, sh_T2;
  __shared__ int sh_K1, sh_K2;
  __shared__ uint32_t sh_scnt;

  int bc = blockIdx.x;
  int tid = threadIdx.x;
  const uint64_t* mycand = cand + (size_t)bc * (size_t)cap;
  int n = min((int)cnt[bc], cap);

  sbuf[tid] = 0; sbuf[tid + 1024] = 0;
  __syncthreads();

  if (n <= 2048) {
    for (int i = tid; i < n; i += 1024) sbuf[i] = mycand[i];
  } else {
    for (int i = tid; i < 4096; i += 1024) hist[i] = 0;
    __syncthreads();
    for (int i = tid; i < n; i += 1024) {
      uint32_t f = (uint32_t)(mycand[i] >> 32);
      atomicAdd(&hist[f >> 20], 1u);
    }
    __syncthreads();
    findThreshold(hist, gsum, KTOP, &sh_T1, &sh_K1, tid);
    __syncthreads();
    uint32_t T1 = sh_T1;
    int Krem = sh_K1;

    for (int i = tid; i < 4096; i += 1024) hist[i] = 0;
    __syncthreads();
    for (int i = tid; i < n; i += 1024) {
      uint32_t f = (uint32_t)(mycand[i] >> 32);
      if ((f >> 20) == T1) atomicAdd(&hist[(f >> 8) & 0xFFFu], 1u);
    }
    __syncthreads();
    findThreshold(hist, gsum, Krem, &sh_T2, &sh_K2, tid);
    __syncthreads();
    uint32_t thresh = (T1 << 20) | (sh_T2 << 8);
    if (tid == 0) sh_scnt = 0;
    __syncthreads();
    for (int i = tid; i < n; i += 1024) {
      uint64_t kk = mycand[i];
      uint32_t f = (uint32_t)(kk >> 32);
      if (f >= thresh) {
        uint32_t p = atomicAdd(&sh_scnt, 1u);
        if (p < 2048) sbuf[p] = kk;
      }
    }
  }
  __syncthreads();

  bitonic2048_desc(sbuf, tid);

  if (tid < KTOP) {
    uint64_t kk = sbuf[tid];
    float score; uint32_t idx;
    if (kk == 0ull) { score = 0.0f; idx = 0u; }
    else {
      uint32_t f = (uint32_t)(kk >> 32);
      idx = ~(uint32_t)kk;
      float v = unflipbits(f);
      score = 1.0f / (1.0f + expf(-v));
    }
    s1_scores[bc * 512 + tid] = score;
    s1_inds  [bc * 512 + tid] = idx;
  }
}

// ---------------- Kernel 3: per-batch top-500 of 1500 + gather + emit ----------------
__global__ __launch_bounds__(1024) void k_final(
    const float* __restrict__ s1_scores, const uint32_t* __restrict__ s1_inds,
    const float* __restrict__ cen_offset, const float* __restrict__ direction,
    const float* __restrict__ z_coor, const float* __restrict__ dimf,
    float* __restrict__ out)
{
  __shared__ uint64_t sbuf[2048];
  int b = blockIdx.x;
  int tid = threadIdx.x;
  sbuf[tid] = 0; sbuf[tid + 1024] = 0;
  __syncthreads();
  for (int i = tid; i < Cn * KTOP; i += 1024) {
    int c = i / KTOP, r = i % KTOP;
    float s = s1_scores[(b * Cn + c) * 512 + r];
    sbuf[i] = ((uint64_t)flipbits(s) << 32) | (uint32_t)(~(uint32_t)i);
  }
  __syncthreads();

  bitonic2048_desc(sbuf, tid);

  if (tid < KTOP) {
    uint64_t kk = sbuf[tid];
    uint32_t pos = ~(uint32_t)kk;
    int c = (int)(pos / KTOP), r = (int)(pos % KTOP);
    int bc = b * Cn + c;
    float score = s1_scores[bc * 512 + r];
    uint32_t ind = s1_inds[bc * 512 + r];
    float x = (float)(ind & (Wd - 1));
    float y = (float)(ind >> 9);
    const float* co = cen_offset + (size_t)b * 2 * HWp;
    const float* di = direction  + (size_t)b * 2 * HWp;
    const float* zc = z_coor     + (size_t)b * HWp;
    const float* dm = dimf       + (size_t)b * 3 * HWp;
    float o[10];
    o[0] = score;
    o[1] = x + co[ind];
    o[2] = y + co[HWp + ind];
    o[3] = zc[ind];
    o[4] = dm[ind];
    o[5] = dm[HWp + ind];
    o[6] = dm[2 * HWp + ind];
    o[7] = di[ind];
    o[8] = di[HWp + ind];
    o[9] = (float)c;
    float* op = out + ((size_t)b * KTOP + tid) * 10;
    #pragma unroll
    for (int q = 0; q < 10; ++q) op[q] = o[q];
  }
}

extern "C" void kernel_launch(void* const* d_in, const int* in_sizes, int n_in,
                              void* d_out, int out_size, void* d_ws, size_t ws_size,
                              hipStream_t stream)
{
  const float* hm         = (const float*)d_in[0];
  const float* cen_offset = (const float*)d_in[1];
  const float* direction  = (const float*)d_in[2];
  const float* z_coor     = (const float*)d_in[3];
  const float* dimf       = (const float*)d_in[4];
  float* out = (float*)d_out;

  // ws layout: cnt[64] u32 | s1_scores[48*512] f32 | s1_inds[48*512] u32 | cand[48*cap] u64
  char* ws = (char*)d_ws;
  uint32_t* cnt      = (uint32_t*)ws;
  float*    s1_sc    = (float*)(ws + 256);
  uint32_t* s1_id    = (uint32_t*)(ws + 256 + NMAP * 512 * 4);
  size_t fixed       = 256 + (size_t)NMAP * 512 * 4 * 2;
  uint64_t* cand     = (uint64_t*)(ws + fixed);

  int cap = 40960;
  if (ws_size < fixed + (size_t)NMAP * (size_t)cap * 8) {
    size_t avail = (ws_size > fixed) ? (ws_size - fixed) : 0;
    cap = (int)(avail / ((size_t)NMAP * 8));
    if (cap < 2048) cap = 2048;  // last-ditch; expected never hit
  }

  hipMemsetAsync(d_ws, 0, 256, stream);
  k_nms_compact<<<NMAP * SLICES, 256, 0, stream>>>(hm, cand, cnt, cap);
  k_select<<<NMAP, 1024, 0, stream>>>(cand, cnt, cap, s1_sc, s1_id);
  k_final<<<Bn, 1024, 0, stream>>>(s1_sc, s1_id, cen_offset, direction, z_coor, dimf, out);
}

// Round 2
// 135.394 us; speedup vs baseline: 8.0051x; 8.0051x over previous
//
#include <hip/hip_runtime.h>
#include <math.h>
#include <float.h>

#define Hd 512
#define Wd 512
#define HWp (Hd*Wd)
#define Bn 16
#define Cn 3
#define NMAP (Bn*Cn)
#define KTOP 500
#define SLICES 32
#define ROWS_PER (Hd/SLICES)
#define SLICE_CAP_MAX 2048

__device__ __forceinline__ uint32_t flipbits(float v){
  uint32_t u = __float_as_uint(v);
  return u ^ (0x80000000u | (uint32_t)(-(int32_t)(u>>31)));
}
__device__ __forceinline__ float unflipbits(uint32_t f){
  uint32_t u = f ^ ((f>>31)? 0x80000000u : 0xFFFFFFFFu);
  return __uint_as_float(u);
}

// ---------------- Kernel 1: NMS (raw domain) + peak compaction, block-private segments ----------------
__global__ __launch_bounds__(256) void k_nms_compact(
    const float* __restrict__ hm, uint64_t* __restrict__ cand,
    uint32_t* __restrict__ cnt, int sliceCap)
{
  __shared__ uint64_t stage[SLICE_CAP_MAX];
  __shared__ uint32_t lcnt;
  int bc    = blockIdx.x / SLICES;
  int slice = blockIdx.x % SLICES;
  const float* map = hm + (size_t)bc * HWp;
  uint64_t* myseg = cand + ((size_t)bc * SLICES + slice) * (size_t)sliceCap;
  int y0 = slice * ROWS_PER;
  int tid = threadIdx.x;
  if (tid == 0) lcnt = 0;
  __syncthreads();

  const int QW = Wd / 4;                 // quads per row
  const int nquads = ROWS_PER * QW;      // 2048, divisible by 256 -> uniform trip count

  for (int q = tid; q < nquads; q += 256) {
    int y  = y0 + q / QW;
    int x4 = (q % QW) * 4;
    float e[3][6];
    #pragma unroll
    for (int r = 0; r < 3; ++r) {
      int yy = y + r - 1;
      if (yy >= 0 && yy < Hd) {
        const float* rw = map + (size_t)yy * Wd;
        float4 cc = *(const float4*)(rw + x4);
        e[r][0] = (x4 > 0)      ? rw[x4 - 1] : -INFINITY;
        e[r][1] = cc.x; e[r][2] = cc.y; e[r][3] = cc.z; e[r][4] = cc.w;
        e[r][5] = (x4 + 4 < Wd) ? rw[x4 + 4] : -INFINITY;
      } else {
        #pragma unroll
        for (int t = 0; t < 6; ++t) e[r][t] = -INFINITY;
      }
    }
    uint64_t keys[4]; int np = 0;
    #pragma unroll
    for (int j = 0; j < 4; ++j) {
      float v = e[1][j + 1];
      bool peak =
        (v >= e[0][j]) && (v >= e[0][j+1]) && (v >= e[0][j+2]) &&
        (v >= e[1][j])                     && (v >= e[1][j+2]) &&
        (v >= e[2][j]) && (v >= e[2][j+1]) && (v >= e[2][j+2]);
      if (peak) {
        uint32_t idx = (uint32_t)(y * Wd + x4 + j);
        keys[np++] = ((uint64_t)flipbits(v) << 32) | (uint32_t)(~idx);
      }
    }
    if (np) {
      uint32_t p = atomicAdd(&lcnt, (uint32_t)np);
      #pragma unroll
      for (int t = 0; t < 4; ++t)
        if (t < np && p + t < SLICE_CAP_MAX) stage[p + t] = keys[t];
    }
  }
  __syncthreads();
  uint32_t n = lcnt;
  if (n > (uint32_t)sliceCap) n = (uint32_t)sliceCap;
  if (n > SLICE_CAP_MAX) n = SLICE_CAP_MAX;
  for (uint32_t i = tid; i < n; i += 256) myseg[i] = stage[i];
  if (tid == 0) cnt[bc * SLICES + slice] = n;
}

// ---------------- radix-select helper: find bin where cumsum-from-top crosses target
__device__ void findThreshold(uint32_t* hist, uint32_t* gsum, int target,
                              uint32_t* outBin, int* outKrem, int tid)
{
  uint32_t s = hist[4*tid] + hist[4*tid+1] + hist[4*tid+2] + hist[4*tid+3];
  gsum[tid] = s;
  __syncthreads();
  for (int d = 1; d < 1024; d <<= 1) {
    uint32_t v = (tid + d < 1024) ? gsum[tid + d] : 0u;
    __syncthreads();
    gsum[tid] += v;
    __syncthreads();
  }
  // gsum[t] = sum over groups >= t. Find largest t with gsum[t] >= target.
  if (gsum[tid] >= (uint32_t)target && (tid == 1023 || gsum[tid+1] < (uint32_t)target)) {
    uint32_t cum = (tid == 1023) ? 0u : gsum[tid+1];
    for (int b = 4*tid + 3; b >= 4*tid; --b) {
      cum += hist[b];
      if (cum >= (uint32_t)target) {
        *outBin  = (uint32_t)b;
        *outKrem = target - (int)(cum - hist[b]);
        break;
      }
    }
  }
  __syncthreads();
}

__device__ void bitonic2048_desc(uint64_t* a, int tid)
{
  for (int k = 2; k <= 2048; k <<= 1) {
    for (int j = k >> 1; j > 0; j >>= 1) {
      for (int i = tid; i < 2048; i += 1024) {
        int ixj = i ^ j;
        if (ixj > i) {
          uint64_t x = a[i], y = a[ixj];
          bool desc = ((i & k) == 0);
          if (desc ? (x < y) : (x > y)) { a[i] = y; a[ixj] = x; }
        }
      }
      __syncthreads();
    }
  }
}

// ---------------- Kernel 2: per-(b,c) top-500 via 2-level radix select + sort ----------------
__global__ __launch_bounds__(1024) void k_select(
    const uint64_t* __restrict__ cand, const uint32_t* __restrict__ cnt, int sliceCap,
    float* __restrict__ s1_scores, uint32_t* __restrict__ s1_inds)
{
  __shared__ uint32_t hist[4096];
  __shared__ uint32_t gsum[1024];
  __shared__ uint64_t sbuf[2048];
  __shared__ uint32_t segn[SLICES];
  __shared__ uint32_t segoff[SLICES];
  __shared__ uint32_t sh_tot;
  __shared__ uint32_t sh_T1, sh_T2;
  __shared__ int sh_K1, sh_K2;
  __shared__ uint32_t sh_scnt;

  int bc = blockIdx.x;
  int tid = threadIdx.x;
  const uint64_t* mycand = cand + (size_t)bc * SLICES * (size_t)sliceCap;

  if (tid < SLICES) segn[tid] = min(cnt[bc * SLICES + tid], (uint32_t)sliceCap);
  __syncthreads();
  if (tid == 0) {
    uint32_t a = 0;
    for (int s = 0; s < SLICES; ++s) { segoff[s] = a; a += segn[s]; }
    sh_tot = a;
  }
  sbuf[tid] = 0; sbuf[tid + 1024] = 0;
  __syncthreads();
  int n = (int)sh_tot;

  if (n <= 2048) {
    for (int s = 0; s < SLICES; ++s) {
      const uint64_t* seg = mycand + (size_t)s * sliceCap;
      for (int i = tid; i < (int)segn[s]; i += 1024) sbuf[segoff[s] + i] = seg[i];
    }
  } else {
    for (int i = tid; i < 4096; i += 1024) hist[i] = 0;
    __syncthreads();
    for (int s = 0; s < SLICES; ++s) {
      const uint64_t* seg = mycand + (size_t)s * sliceCap;
      for (int i = tid; i < (int)segn[s]; i += 1024) {
        uint32_t f = (uint32_t)(seg[i] >> 32);
        atomicAdd(&hist[f >> 20], 1u);
      }
    }
    __syncthreads();
    findThreshold(hist, gsum, KTOP, &sh_T1, &sh_K1, tid);
    __syncthreads();
    uint32_t T1 = sh_T1;
    int Krem = sh_K1;

    for (int i = tid; i < 4096; i += 1024) hist[i] = 0;
    __syncthreads();
    for (int s = 0; s < SLICES; ++s) {
      const uint64_t* seg = mycand + (size_t)s * sliceCap;
      for (int i = tid; i < (int)segn[s]; i += 1024) {
        uint32_t f = (uint32_t)(seg[i] >> 32);
        if ((f >> 20) == T1) atomicAdd(&hist[(f >> 8) & 0xFFFu], 1u);
      }
    }
    __syncthreads();
    findThreshold(hist, gsum, Krem, &sh_T2, &sh_K2, tid);
    __syncthreads();
    uint32_t thresh = (T1 << 20) | (sh_T2 << 8);
    if (tid == 0) sh_scnt = 0;
    __syncthreads();
    for (int s = 0; s < SLICES; ++s) {
      const uint64_t* seg = mycand + (size_t)s * sliceCap;
      for (int i = tid; i < (int)segn[s]; i += 1024) {
        uint64_t kk = seg[i];
        uint32_t f = (uint32_t)(kk >> 32);
        if (f >= thresh) {
          uint32_t p = atomicAdd(&sh_scnt, 1u);
          if (p < 2048) sbuf[p] = kk;
        }
      }
    }
  }
  __syncthreads();

  bitonic2048_desc(sbuf, tid);

  if (tid < KTOP) {
    uint64_t kk = sbuf[tid];
    float score; uint32_t idx;
    if (kk == 0ull) { score = 0.0f; idx = 0u; }
    else {
      uint32_t f = (uint32_t)(kk >> 32);
      idx = ~(uint32_t)kk;
      float v = unflipbits(f);
      score = 1.0f / (1.0f + expf(-v));
    }
    s1_scores[bc * 512 + tid] = score;
    s1_inds  [bc * 512 + tid] = idx;
  }
}

// ---------------- Kernel 3: per-batch top-500 of 1500 + gather + emit ----------------
__global__ __launch_bounds__(1024) void k_final(
    const float* __restrict__ s1_scores, const uint32_t* __restrict__ s1_inds,
    const float* __restrict__ cen_offset, const float* __restrict__ direction,
    const float* __restrict__ z_coor, const float* __restrict__ dimf,
    float* __restrict__ out)
{
  __shared__ uint64_t sbuf[2048];
  int b = blockIdx.x;
  int tid = threadIdx.x;
  sbuf[tid] = 0; sbuf[tid + 1024] = 0;
  __syncthreads();
  for (int i = tid; i < Cn * KTOP; i += 1024) {
    int c = i / KTOP, r = i % KTOP;
    float s = s1_scores[(b * Cn + c) * 512 + r];
    sbuf[i] = ((uint64_t)flipbits(s) << 32) | (uint32_t)(~(uint32_t)i);
  }
  __syncthreads();

  bitonic2048_desc(sbuf, tid);

  if (tid < KTOP) {
    uint64_t kk = sbuf[tid];
    uint32_t pos = ~(uint32_t)kk;
    int c = (int)(pos / KTOP), r = (int)(pos % KTOP);
    int bc = b * Cn + c;
    float score = s1_scores[bc * 512 + r];
    uint32_t ind = s1_inds[bc * 512 + r];
    float x = (float)(ind & (Wd - 1));
    float y = (float)(ind >> 9);
    const float* co = cen_offset + (size_t)b * 2 * HWp;
    const float* di = direction  + (size_t)b * 2 * HWp;
    const float* zc = z_coor     + (size_t)b * HWp;
    const float* dm = dimf       + (size_t)b * 3 * HWp;
    float o[10];
    o[0] = score;
    o[1] = x + co[ind];
    o[2] = y + co[HWp + ind];
    o[3] = zc[ind];
    o[4] = dm[ind];
    o[5] = dm[HWp + ind];
    o[6] = dm[2 * HWp + ind];
    o[7] = di[ind];
    o[8] = di[HWp + ind];
    o[9] = (float)c;
    float* op = out + ((size_t)b * KTOP + tid) * 10;
    #pragma unroll
    for (int q = 0; q < 10; ++q) op[q] = o[q];
  }
}

extern "C" void kernel_launch(void* const* d_in, const int* in_sizes, int n_in,
                              void* d_out, int out_size, void* d_ws, size_t ws_size,
                              hipStream_t stream)
{
  const float* hm         = (const float*)d_in[0];
  const float* cen_offset = (const float*)d_in[1];
  const float* direction  = (const float*)d_in[2];
  const float* z_coor     = (const float*)d_in[3];
  const float* dimf       = (const float*)d_in[4];
  float* out = (float*)d_out;

  // ws layout: cnt[NMAP*SLICES] u32 (pad 8KB) | s1_scores[48*512] f32 | s1_inds[48*512] u32 | cand[48*32*sliceCap] u64
  char* ws = (char*)d_ws;
  uint32_t* cnt   = (uint32_t*)ws;
  float*    s1_sc = (float*)(ws + 8192);
  uint32_t* s1_id = (uint32_t*)(ws + 8192 + NMAP * 512 * 4);
  size_t fixed    = 8192 + (size_t)NMAP * 512 * 4 * 2;
  uint64_t* cand  = (uint64_t*)(ws + fixed);

  int sliceCap = SLICE_CAP_MAX;  // 2048 = provable worst-case peaks per 16x512 slice
  size_t need = fixed + (size_t)NMAP * SLICES * (size_t)sliceCap * 8;
  if (ws_size < need) {
    size_t avail = (ws_size > fixed) ? (ws_size - fixed) : 0;
    sliceCap = (int)(avail / ((size_t)NMAP * SLICES * 8));
    if (sliceCap > SLICE_CAP_MAX) sliceCap = SLICE_CAP_MAX;
    if (sliceCap < 256) sliceCap = 256;  // last-ditch; expected never hit
  }

  k_nms_compact<<<NMAP * SLICES, 256, 0, stream>>>(hm, cand, cnt, sliceCap);
  k_select<<<NMAP, 1024, 0, stream>>>(cand, cnt, sliceCap, s1_sc, s1_id);
  k_final<<<Bn, 1024, 0, stream>>>(s1_sc, s1_id, cen_offset, direction, z_coor, dimf, out);
}

// Round 3
// 124.391 us; speedup vs baseline: 8.7133x; 1.0885x over previous
//
#include <hip/hip_runtime.h>
#include <math.h>
#include <float.h>

#define Hd 512
#define Wd 512
#define HWp (Hd*Wd)
#define Bn 16
#define Cn 3
#define NMAP (Bn*Cn)
#define KTOP 500
#define SLICES 32
#define ROWS_PER (Hd/SLICES)
#define SLICE_CAP_MAX 2048
#define QPR 128   // float4 quads per row

__device__ __forceinline__ uint32_t flipbits(float v){
  uint32_t u = __float_as_uint(v);
  return u ^ (0x80000000u | (uint32_t)(-(int32_t)(u>>31)));
}
__device__ __forceinline__ float unflipbits(uint32_t f){
  uint32_t u = f ^ ((f>>31)? 0x80000000u : 0xFFFFFFFFu);
  return __uint_as_float(u);
}

// ============ Kernel 1: separable NMS + peak compaction + per-map 12-bit hist ============
__global__ __launch_bounds__(256) void k_nms_compact(
    const float* __restrict__ hm, uint64_t* __restrict__ cand,
    uint32_t* __restrict__ cnt, uint32_t* __restrict__ ghist, int sliceCap)
{
  __shared__ uint64_t stage[SLICE_CAP_MAX];
  __shared__ uint32_t lhist[4096];
  __shared__ float vxs[2][2][QPR+2];   // [row parity][half][quad] : vm.x, sentinels at 0 / QPR+1
  __shared__ float vws[2][2][QPR+2];   // vm.w
  __shared__ uint32_t lcnt;

  const int bc    = blockIdx.x / SLICES;
  const int slice = blockIdx.x % SLICES;
  const float* map = hm + (size_t)bc * HWp;
  uint64_t* myseg = cand + ((size_t)bc * SLICES + slice) * (size_t)sliceCap;
  const int tid = threadIdx.x;
  const int q   = tid & (QPR - 1);
  const int h   = tid >> 7;
  const int x4  = q * 4;
  const uint32_t cap = (uint32_t)((sliceCap < SLICE_CAP_MAX) ? sliceCap : SLICE_CAP_MAX);

  if (tid == 0) lcnt = 0;
  for (int i = tid; i < 4096; i += 256) lhist[i] = 0;
  if (tid < 8) {
    int pr = tid & 1, hh = (tid >> 1) & 1, side = tid >> 2;
    vxs[pr][hh][side ? (QPR + 1) : 0] = -INFINITY;
    vws[pr][hh][side ? (QPR + 1) : 0] = -INFINITY;
  }

  const int ybase = slice * ROWS_PER + h * (ROWS_PER / 2);
  const float4 NEG4 = make_float4(-INFINITY, -INFINITY, -INFINITY, -INFINITY);
  float4 o_prev = (ybase > 0) ? *(const float4*)(map + (size_t)(ybase - 1) * Wd + x4) : NEG4;
  float4 o_cur  = *(const float4*)(map + (size_t)ybase * Wd + x4);
  __syncthreads();

  #pragma unroll
  for (int r = 0; r < ROWS_PER / 2; ++r) {
    const int y  = ybase + r;
    const int yn = y + 1;
    float4 o_next = (yn < Hd) ? *(const float4*)(map + (size_t)yn * Wd + x4) : NEG4;
    float4 vm;
    vm.x = fmaxf(fmaxf(o_prev.x, o_cur.x), o_next.x);
    vm.y = fmaxf(fmaxf(o_prev.y, o_cur.y), o_next.y);
    vm.z = fmaxf(fmaxf(o_prev.z, o_cur.z), o_next.z);
    vm.w = fmaxf(fmaxf(o_prev.w, o_cur.w), o_next.w);
    const int pr = r & 1;
    vxs[pr][h][q + 1] = vm.x;
    vws[pr][h][q + 1] = vm.w;
    __syncthreads();
    const float hl = vws[pr][h][q];       // left neighbor's vm.w
    const float hr = vxs[pr][h][q + 2];   // right neighbor's vm.x
    float m0 = fmaxf(fmaxf(hl,   vm.x), vm.y);
    float m1 = fmaxf(fmaxf(vm.x, vm.y), vm.z);
    float m2 = fmaxf(fmaxf(vm.y, vm.z), vm.w);
    float m3 = fmaxf(fmaxf(vm.z, vm.w), hr);
    uint64_t keys[4]; uint32_t np = 0;
    const uint32_t ibase = (uint32_t)(y * Wd + x4);
    if (o_cur.x >= m0) keys[np++] = ((uint64_t)flipbits(o_cur.x) << 32) | (uint32_t)(~(ibase    ));
    if (o_cur.y >= m1) keys[np++] = ((uint64_t)flipbits(o_cur.y) << 32) | (uint32_t)(~(ibase + 1));
    if (o_cur.z >= m2) keys[np++] = ((uint64_t)flipbits(o_cur.z) << 32) | (uint32_t)(~(ibase + 2));
    if (o_cur.w >= m3) keys[np++] = ((uint64_t)flipbits(o_cur.w) << 32) | (uint32_t)(~(ibase + 3));
    if (np) {
      uint32_t p = atomicAdd(&lcnt, np);
      #pragma unroll
      for (uint32_t t = 0; t < 4; ++t)
        if (t < np && (p + t) < cap) {
          stage[p + t] = keys[t];
          atomicAdd(&lhist[(uint32_t)(keys[t] >> 52)], 1u);
        }
    }
    o_prev = o_cur; o_cur = o_next;
  }
  __syncthreads();
  uint32_t n = lcnt; if (n > cap) n = cap;
  for (uint32_t i = tid; i < n; i += 256) myseg[i] = stage[i];
  if (tid == 0) cnt[bc * SLICES + slice] = n;
  uint32_t* gh = ghist + (size_t)bc * 4096;
  for (int i = tid; i < 4096; i += 256) {
    uint32_t v = lhist[i];
    if (v) atomicAdd(&gh[i], v);   // <=32 adds per word per map
  }
}

// ============ shfl-based suffix-scan threshold finder (2 barriers) ============
// out3: [0]=bin, [1]=krem, [2]=M (count of keys in groups/bins >= bin)
__device__ __forceinline__ void findThreshold2(
    const uint32_t* hist, uint32_t target, int tid, int lane, int wid,
    uint32_t* wtot, uint32_t* out3)
{
  uint32_t s = hist[4*tid] + hist[4*tid+1] + hist[4*tid+2] + hist[4*tid+3];
  uint32_t v = s;
  #pragma unroll
  for (int d = 1; d < 64; d <<= 1) {
    uint32_t u = __shfl_down(v, d);
    if (lane + d < 64) v += u;
  }
  if (lane == 0) wtot[wid] = v;
  __syncthreads();
  uint32_t above = 0;
  for (int w = wid + 1; w < 16; ++w) above += wtot[w];
  uint32_t gsuf = v + above;                 // count in thread-groups >= tid
  if (gsuf >= target && (gsuf - s) < target) {
    uint32_t cum = gsuf - s;
    for (int b = 4*tid + 3; b >= 4*tid; --b) {
      cum += hist[b];
      if (cum >= target) {
        out3[0] = (uint32_t)b;
        out3[1] = target - (cum - hist[b]);
        out3[2] = cum;
        break;
      }
    }
  }
  __syncthreads();
}

// ============ register-resident bitonic sort, 2048 keys desc, 1024 threads ============
__device__ __forceinline__ uint64_t cexch(uint64_t mine, uint64_t part, bool wantMax) {
  uint64_t mx = mine > part ? mine : part;
  uint64_t mn = mine > part ? part : mine;
  return wantMax ? mx : mn;
}

__device__ void bitonic2048_reg(uint64_t& e0, uint64_t& e1, uint64_t* sbuf, int tid, int lane)
{
  const int i1 = tid + 1024;
  for (int k = 2; k <= 2048; k <<= 1) {
    for (int j = k >> 1; j > 0; j >>= 1) {
      if (j >= 1024) {                       // partner is in-thread (only k=2048, j=1024)
        uint64_t mx = e0 > e1 ? e0 : e1;
        uint64_t mn = e0 > e1 ? e1 : e0;
        e0 = mx; e1 = mn;
      } else if (j >= 64) {                  // cross-wave via LDS
        __syncthreads();
        sbuf[tid] = e0; sbuf[i1] = e1;
        __syncthreads();
        uint64_t p0 = sbuf[tid ^ j];
        uint64_t p1 = sbuf[i1 ^ j];
        bool amS = ((tid & j) == 0);
        e0 = cexch(e0, p0, ((tid & k) == 0) == amS);
        e1 = cexch(e1, p1, ((i1  & k) == 0) == amS);
      } else {                               // intra-wave via shfl, no barrier
        uint64_t p0 = __shfl_xor((unsigned long long)e0, j);
        uint64_t p1 = __shfl_xor((unsigned long long)e1, j);
        bool amS = ((lane & j) == 0);
        e0 = cexch(e0, p0, ((tid & k) == 0) == amS);
        e1 = cexch(e1, p1, ((i1  & k) == 0) == amS);
      }
    }
  }
  __syncthreads();
  sbuf[tid] = e0; sbuf[i1] = e1;
  __syncthreads();
}

// ============ Kernel 2: per-(b,c) top-500 ============
__global__ __launch_bounds__(1024) void k_select(
    const uint64_t* __restrict__ cand, const uint32_t* __restrict__ cnt,
    const uint32_t* __restrict__ ghist, int sliceCap,
    float* __restrict__ s1_scores, uint32_t* __restrict__ s1_inds)
{
  __shared__ uint32_t hist[4096];
  __shared__ uint64_t sbuf[2048];
  __shared__ uint32_t segn[SLICES];
  __shared__ uint32_t wtot[16];
  __shared__ uint32_t res[4];   // 0:bin 1:krem 2:M 3:append counter
  __shared__ uint32_t sh_n;

  const int bc = blockIdx.x, tid = threadIdx.x;
  const int lane = tid & 63, wid = tid >> 6;
  const uint64_t* mycand = cand + (size_t)bc * SLICES * (size_t)sliceCap;

  if (wid == 0) {
    uint32_t v = 0;
    if (lane < SLICES) { v = min(cnt[bc*SLICES+lane], (uint32_t)sliceCap); segn[lane] = v; }
    #pragma unroll
    for (int d = 1; d < 64; d <<= 1) { uint32_t u = __shfl_down(v, d); if (lane + d < 64) v += u; }
    if (lane == 0) sh_n = v;
  }
  for (int i = tid; i < 4096; i += 1024) hist[i] = ghist[(size_t)bc*4096 + i];
  sbuf[tid] = 0; sbuf[tid + 1024] = 0;
  if (tid == 0) res[3] = 0;
  __syncthreads();
  const uint32_t n = sh_n;

  if (n <= 2048) {
    for (int s = 0; s < SLICES; ++s) {
      const uint64_t* seg = mycand + (size_t)s * sliceCap;
      const uint32_t sn = segn[s];
      for (uint32_t i = tid; i < sn; i += 1024) {
        uint32_t p = atomicAdd(&res[3], 1u);
        sbuf[p] = seg[i];
      }
    }
    __syncthreads();
  } else {
    findThreshold2(hist, KTOP, tid, lane, wid, wtot, res);   // ends with barrier
    const uint32_t T1 = res[0], krem = res[1], M = res[2];
    uint32_t thresh;
    if (M <= 2048) {
      thresh = T1 << 20;           // all survivors fit: single scan, exact
    } else {
      // rare: refine 12 more bits
      __syncthreads();
      for (int i = tid; i < 4096; i += 1024) hist[i] = 0;
      __syncthreads();
      for (int s = 0; s < SLICES; ++s) {
        const uint64_t* seg = mycand + (size_t)s * sliceCap;
        const uint32_t sn = segn[s];
        for (uint32_t i = tid; i < sn; i += 1024) {
          uint32_t f = (uint32_t)(seg[i] >> 32);
          if ((f >> 20) == T1) atomicAdd(&hist[(f >> 8) & 0xFFFu], 1u);
        }
      }
      __syncthreads();
      findThreshold2(hist, krem, tid, lane, wid, wtot, res);
      thresh = (T1 << 20) | (res[0] << 8);
    }
    for (int s = 0; s < SLICES; ++s) {
      const uint64_t* seg = mycand + (size_t)s * sliceCap;
      const uint32_t sn = segn[s];
      for (uint32_t i = tid; i < sn; i += 1024) {
        uint64_t kk = seg[i];
        if ((uint32_t)(kk >> 32) >= thresh) {
          uint32_t p = atomicAdd(&res[3], 1u);
          if (p < 2048) sbuf[p] = kk;
        }
      }
    }
    __syncthreads();
  }

  uint64_t e0 = sbuf[tid], e1 = sbuf[tid + 1024];
  bitonic2048_reg(e0, e1, sbuf, tid, lane);

  if (tid < KTOP) {
    uint64_t kk = sbuf[tid];
    float score; uint32_t idx;
    if (kk == 0ull) { score = 0.0f; idx = 0u; }
    else {
      uint32_t f = (uint32_t)(kk >> 32);
      idx = ~(uint32_t)kk;
      float v = unflipbits(f);
      score = 1.0f / (1.0f + expf(-v));
    }
    s1_scores[bc * 512 + tid] = score;
    s1_inds  [bc * 512 + tid] = idx;
  }
}

// ============ Kernel 3: per-batch top-500 of 1500 + gather + emit ============
__global__ __launch_bounds__(1024) void k_final(
    const float* __restrict__ s1_scores, const uint32_t* __restrict__ s1_inds,
    const float* __restrict__ cen_offset, const float* __restrict__ direction,
    const float* __restrict__ z_coor, const float* __restrict__ dimf,
    float* __restrict__ out)
{
  __shared__ uint64_t sbuf[2048];
  const int b = blockIdx.x, tid = threadIdx.x, lane = tid & 63;

  uint64_t e0 = 0, e1 = 0;
  if (tid < Cn * KTOP) {
    int c = tid / KTOP, r = tid % KTOP;
    float s = s1_scores[(b * Cn + c) * 512 + r];
    e0 = ((uint64_t)flipbits(s) << 32) | (uint32_t)(~(uint32_t)tid);
  }
  {
    int t1 = tid + 1024;
    if (t1 < Cn * KTOP) {
      int c = t1 / KTOP, r = t1 % KTOP;
      float s = s1_scores[(b * Cn + c) * 512 + r];
      e1 = ((uint64_t)flipbits(s) << 32) | (uint32_t)(~(uint32_t)t1);
    }
  }
  bitonic2048_reg(e0, e1, sbuf, tid, lane);

  const float* co = cen_offset + (size_t)b * 2 * HWp;
  const float* di = direction  + (size_t)b * 2 * HWp;
  const float* zc = z_coor     + (size_t)b * HWp;
  const float* dm = dimf       + (size_t)b * 3 * HWp;

  for (int t = tid; t < KTOP * 10; t += 1024) {
    int item = t / 10, qf = t - item * 10;
    uint64_t kk = sbuf[item];
    uint32_t pos = ~(uint32_t)kk;
    int c = (int)(pos / KTOP), r = (int)(pos - (uint32_t)c * KTOP);
    int bcx = b * Cn + c;
    uint32_t ind = s1_inds[bcx * 512 + r];
    float val;
    switch (qf) {
      case 0: val = s1_scores[bcx * 512 + r]; break;
      case 1: val = (float)(ind & (Wd - 1)) + co[ind]; break;
      case 2: val = (float)(ind >> 9) + co[HWp + ind]; break;
      case 3: val = zc[ind]; break;
      case 4: val = dm[ind]; break;
      case 5: val = dm[HWp + ind]; break;
      case 6: val = dm[2 * HWp + ind]; break;
      case 7: val = di[ind]; break;
      case 8: val = di[HWp + ind]; break;
      default: val = (float)c; break;
    }
    out[((size_t)b * KTOP + item) * 10 + qf] = val;
  }
}

extern "C" void kernel_launch(void* const* d_in, const int* in_sizes, int n_in,
                              void* d_out, int out_size, void* d_ws, size_t ws_size,
                              hipStream_t stream)
{
  const float* hm         = (const float*)d_in[0];
  const float* cen_offset = (const float*)d_in[1];
  const float* direction  = (const float*)d_in[2];
  const float* z_coor     = (const float*)d_in[3];
  const float* dimf       = (const float*)d_in[4];
  float* out = (float*)d_out;

  // ws: cnt[1536]u32 pad8K | ghist[48*4096]u32 | s1_sc | s1_id | cand
  char* ws = (char*)d_ws;
  uint32_t* cnt   = (uint32_t*)ws;
  uint32_t* ghist = (uint32_t*)(ws + 8192);
  size_t off      = 8192 + (size_t)NMAP * 4096 * 4;
  float*    s1_sc = (float*)(ws + off);
  uint32_t* s1_id = (uint32_t*)(ws + off + (size_t)NMAP * 512 * 4);
  size_t fixed    = off + (size_t)NMAP * 512 * 4 * 2;
  uint64_t* cand  = (uint64_t*)(ws + fixed);

  int sliceCap = SLICE_CAP_MAX;
  size_t need = fixed + (size_t)NMAP * SLICES * (size_t)sliceCap * 8;
  if (ws_size < need) {
    size_t avail = (ws_size > fixed) ? (ws_size - fixed) : 0;
    sliceCap = (int)(avail / ((size_t)NMAP * SLICES * 8));
    if (sliceCap > SLICE_CAP_MAX) sliceCap = SLICE_CAP_MAX;
    if (sliceCap < 256) sliceCap = 256;
  }

  hipMemsetAsync(d_ws, 0, off, stream);   // cnt + ghist
  k_nms_compact<<<NMAP * SLICES, 256, 0, stream>>>(hm, cand, cnt, ghist, sliceCap);
  k_select<<<NMAP, 1024, 0, stream>>>(cand, cnt, ghist, sliceCap, s1_sc, s1_id);
  k_final<<<Bn, 1024, 0, stream>>>(s1_sc, s1_id, cen_offset, direction, z_coor, dimf, out);
}

// Round 4
// 90.438 us; speedup vs baseline: 11.9845x; 1.3754x over previous
//
#include <hip/hip_runtime.h>
#include <math.h>
#include <float.h>

#define Hd 512
#define Wd 512
#define HWp (Hd*Wd)
#define Bn 16
#define Cn 3
#define NMAP (Bn*Cn)
#define KTOP 500
#define SLICES 16
#define ROWS_SL 32          // rows per slice
#define WPB 4               // waves per block
#define ROWS_W 8            // rows per wave
#define SEGS (SLICES*WPB)   // 64 private segments per map
#define CAPW_MAX 1024       // worst-case peaks in an 8-row band = 4*256 = 1024

__device__ __forceinline__ uint32_t flipbits(float v){
  uint32_t u = __float_as_uint(v);
  return u ^ (0x80000000u | (uint32_t)(-(int32_t)(u>>31)));
}
__device__ __forceinline__ float unflipbits(uint32_t f){
  uint32_t u = f ^ ((f>>31)? 0x80000000u : 0xFFFFFFFFu);
  return __uint_as_float(u);
}

// ============ Kernel 1: NMS, wave-per-row, no LDS / barriers / atomics ============
__global__ __launch_bounds__(256) void k_nms(
    const float* __restrict__ hm, uint64_t* __restrict__ cand,
    uint32_t* __restrict__ cnt, int capw)
{
  const int bc    = blockIdx.x / SLICES;
  const int slice = blockIdx.x % SLICES;
  const int tid   = threadIdx.x;
  const int lane  = tid & 63;
  const int w     = tid >> 6;
  const float* map = hm + (size_t)bc * HWp;
  const int segid = (bc*SLICES + slice)*WPB + w;
  uint64_t* seg = cand + (size_t)segid * (size_t)capw;
  const int y0 = slice*ROWS_SL + w*ROWS_W;
  const int xb = lane*8;
  const float4 NEG4 = make_float4(-INFINITY,-INFINITY,-INFINITY,-INFINITY);

  float4 p0, p1, c0, c1;
  if (y0 > 0) {
    const float* rp = map + (size_t)(y0-1)*Wd + xb;
    p0 = *(const float4*)rp; p1 = *(const float4*)(rp+4);
  } else { p0 = NEG4; p1 = NEG4; }
  {
    const float* rp = map + (size_t)y0*Wd + xb;
    c0 = *(const float4*)rp; c1 = *(const float4*)(rp+4);
  }

  uint32_t my_off = 0;
  #pragma unroll
  for (int r = 0; r < ROWS_W; ++r) {
    const int y = y0 + r, yn = y + 1;
    float4 n0, n1;
    if (yn < Hd) {
      const float* rp = map + (size_t)yn*Wd + xb;
      n0 = *(const float4*)rp; n1 = *(const float4*)(rp+4);
    } else { n0 = NEG4; n1 = NEG4; }

    float vm0 = fmaxf(fmaxf(p0.x,c0.x),n0.x);
    float vm1 = fmaxf(fmaxf(p0.y,c0.y),n0.y);
    float vm2 = fmaxf(fmaxf(p0.z,c0.z),n0.z);
    float vm3 = fmaxf(fmaxf(p0.w,c0.w),n0.w);
    float vm4 = fmaxf(fmaxf(p1.x,c1.x),n1.x);
    float vm5 = fmaxf(fmaxf(p1.y,c1.y),n1.y);
    float vm6 = fmaxf(fmaxf(p1.z,c1.z),n1.z);
    float vm7 = fmaxf(fmaxf(p1.w,c1.w),n1.w);
    float vmL = __shfl_up(vm7, 1);   if (lane == 0)  vmL = -INFINITY;
    float vmR = __shfl_down(vm0, 1); if (lane == 63) vmR = -INFINITY;

    float m0 = fmaxf(vmL, fmaxf(vm0, vm1));
    float m1 = fmaxf(vm0, fmaxf(vm1, vm2));
    float m2 = fmaxf(vm1, fmaxf(vm2, vm3));
    float m3 = fmaxf(vm2, fmaxf(vm3, vm4));
    float m4 = fmaxf(vm3, fmaxf(vm4, vm5));
    float m5 = fmaxf(vm4, fmaxf(vm5, vm6));
    float m6 = fmaxf(vm5, fmaxf(vm6, vm7));
    float m7 = fmaxf(vm6, fmaxf(vm7, vmR));

    uint32_t pk = 0;
    if (c0.x >= m0) pk |= 1u;
    if (c0.y >= m1) pk |= 2u;
    if (c0.z >= m2) pk |= 4u;
    if (c0.w >= m3) pk |= 8u;
    if (c1.x >= m4) pk |= 16u;
    if (c1.y >= m5) pk |= 32u;
    if (c1.z >= m6) pk |= 64u;
    if (c1.w >= m7) pk |= 128u;
    uint32_t np = (uint32_t)__popc(pk);

    uint32_t v = np;
    #pragma unroll
    for (int d = 1; d < 64; d <<= 1) { uint32_t u = __shfl_up(v, d); if (lane >= d) v += u; }
    uint32_t tot  = __shfl(v, 63);
    uint32_t base = my_off + (v - np);

    const uint32_t ib = (uint32_t)(y*Wd + xb);
    float cv[8]; cv[0]=c0.x; cv[1]=c0.y; cv[2]=c0.z; cv[3]=c0.w;
    cv[4]=c1.x; cv[5]=c1.y; cv[6]=c1.z; cv[7]=c1.w;
    #pragma unroll
    for (int i = 0; i < 8; ++i) {
      if (pk & (1u << i)) {
        uint32_t p = base + (uint32_t)__popc(pk & ((1u << i) - 1u));
        if (p < (uint32_t)capw)
          seg[p] = ((uint64_t)flipbits(cv[i]) << 32) | (uint32_t)(~(ib + (uint32_t)i));
      }
    }
    my_off += tot;
    p0 = c0; p1 = c1; c0 = n0; c1 = n1;
  }
  if (lane == 0) cnt[segid] = (my_off < (uint32_t)capw) ? my_off : (uint32_t)capw;
}

// ============ shfl suffix-scan threshold finder (2 barriers) ============
// res: [0]=bin, [1]=krem, [2]=M
__device__ __forceinline__ void findThreshold2(
    const uint32_t* hist, uint32_t target, int tid, int lane, int wid,
    uint32_t* wtot, uint32_t* res)
{
  uint32_t s = hist[4*tid] + hist[4*tid+1] + hist[4*tid+2] + hist[4*tid+3];
  uint32_t v = s;
  #pragma unroll
  for (int d = 1; d < 64; d <<= 1) { uint32_t u = __shfl_down(v, d); if (lane + d < 64) v += u; }
  if (lane == 0) wtot[wid] = v;
  __syncthreads();
  uint32_t above = 0;
  for (int ww = wid + 1; ww < 16; ++ww) above += wtot[ww];
  uint32_t gsuf = v + above;
  if (gsuf >= target && (gsuf - s) < target) {
    uint32_t cum = gsuf - s;
    for (int b = 4*tid + 3; b >= 4*tid; --b) {
      cum += hist[b];
      if (cum >= target) { res[0]=(uint32_t)b; res[1]=target-(cum-hist[b]); res[2]=cum; break; }
    }
  }
  __syncthreads();
}

// ============ register bitonic sort of 2048 keys (desc), 1024 threads ============
__device__ __forceinline__ uint64_t cexch(uint64_t mine, uint64_t part, bool wantMax) {
  uint64_t mx = mine > part ? mine : part;
  uint64_t mn = mine > part ? part : mine;
  return wantMax ? mx : mn;
}

__device__ void bitonic2048_reg(uint64_t& e0, uint64_t& e1, uint64_t* sbuf, int tid, int lane)
{
  const int i1 = tid + 1024;
  for (int k = 2; k <= 2048; k <<= 1) {
    for (int j = k >> 1; j > 0; j >>= 1) {
      if (j >= 1024) {
        uint64_t mx = e0 > e1 ? e0 : e1;
        uint64_t mn = e0 > e1 ? e1 : e0;
        e0 = mx; e1 = mn;
      } else if (j >= 64) {
        __syncthreads();
        sbuf[tid] = e0; sbuf[i1] = e1;
        __syncthreads();
        uint64_t q0 = sbuf[tid ^ j];
        uint64_t q1 = sbuf[i1 ^ j];
        bool amS = ((tid & j) == 0);
        e0 = cexch(e0, q0, ((tid & k) == 0) == amS);
        e1 = cexch(e1, q1, ((i1  & k) == 0) == amS);
      } else {
        uint64_t q0 = __shfl_xor((unsigned long long)e0, j);
        uint64_t q1 = __shfl_xor((unsigned long long)e1, j);
        bool amS = ((lane & j) == 0);
        e0 = cexch(e0, q0, ((tid & k) == 0) == amS);
        e1 = cexch(e1, q1, ((i1  & k) == 0) == amS);
      }
    }
  }
  __syncthreads();
  sbuf[tid] = e0; sbuf[i1] = e1;
  __syncthreads();
}

__device__ __forceinline__ void wave_append(uint64_t kk, bool keep, uint32_t* ctr,
                                            uint64_t* sbuf, int lane)
{
  unsigned long long mk = __ballot(keep);
  if (!mk) return;
  uint32_t tot = (uint32_t)__popcll(mk);
  uint32_t b = 0;
  if (lane == 0) b = atomicAdd(ctr, tot);
  b = __shfl(b, 0);
  if (keep) {
    uint32_t p = b + (uint32_t)__popcll(mk & ((1ull << lane) - 1ull));
    if (p < 2048) sbuf[p] = kk;
  }
}

// ============ Kernel 2: per-(b,c) top-500 ============
__global__ __launch_bounds__(1024) void k_select(
    const uint64_t* __restrict__ cand, const uint32_t* __restrict__ cnt, int capw,
    float* __restrict__ s1_scores, uint32_t* __restrict__ s1_inds)
{
  __shared__ uint32_t hist[4096];
  __shared__ uint64_t sbuf[2048];
  __shared__ uint32_t segn[SEGS];
  __shared__ uint32_t wtot[16];
  __shared__ uint32_t res[4];     // 0:bin 1:krem 2:M 3:append counter
  __shared__ uint32_t sh_n;

  const int bc = blockIdx.x, tid = threadIdx.x;
  const int lane = tid & 63, wid = tid >> 6;
  const uint64_t* base = cand + (size_t)bc * SEGS * (size_t)capw;

  if (tid < SEGS) segn[tid] = min(cnt[bc*SEGS + tid], (uint32_t)capw);
  for (int i = tid; i < 4096; i += 1024) hist[i] = 0;
  sbuf[tid] = 0; sbuf[tid + 1024] = 0;
  if (tid == 0) res[3] = 0;
  __syncthreads();

  if (wid == 0) {
    uint32_t v = segn[lane];   // SEGS == 64
    #pragma unroll
    for (int d = 1; d < 64; d <<= 1) { uint32_t u = __shfl_down(v, d); if (lane + d < 64) v += u; }
    if (lane == 0) sh_n = v;
  }
  __syncthreads();
  const uint32_t n = sh_n;

  if (n <= 2048) {
    for (int s = wid; s < SEGS; s += 16) {
      const uint64_t* sg = base + (size_t)s * capw;
      const uint32_t sn = segn[s];
      for (uint32_t i = lane; i < ((sn + 63u) & ~63u); i += 64) {
        bool valid = (i < sn);
        uint64_t kk = valid ? sg[i] : 0ull;
        wave_append(kk, valid, &res[3], sbuf, lane);
      }
    }
    __syncthreads();
  } else {
    // pass A: histogram of top-12 bits
    for (int s = wid; s < SEGS; s += 16) {
      const uint64_t* sg = base + (size_t)s * capw;
      const uint32_t sn = segn[s];
      for (uint32_t i = lane; i < sn; i += 64)
        atomicAdd(&hist[(uint32_t)(sg[i] >> 52)], 1u);
    }
    __syncthreads();
    findThreshold2(hist, KTOP, tid, lane, wid, wtot, res);
    const uint32_t T1 = res[0], krem = res[1], M = res[2];
    __syncthreads();
    uint32_t thresh;
    if (M <= 2048) {
      thresh = T1 << 20;
    } else {
      for (int i = tid; i < 4096; i += 1024) hist[i] = 0;
      __syncthreads();
      for (int s = wid; s < SEGS; s += 16) {
        const uint64_t* sg = base + (size_t)s * capw;
        const uint32_t sn = segn[s];
        for (uint32_t i = lane; i < sn; i += 64) {
          uint32_t f = (uint32_t)(sg[i] >> 32);
          if ((f >> 20) == T1) atomicAdd(&hist[(f >> 8) & 0xFFFu], 1u);
        }
      }
      __syncthreads();
      findThreshold2(hist, krem, tid, lane, wid, wtot, res);
      thresh = (T1 << 20) | (res[0] << 8);
      __syncthreads();
    }
    // pass B: compact survivors
    for (int s = wid; s < SEGS; s += 16) {
      const uint64_t* sg = base + (size_t)s * capw;
      const uint32_t sn = segn[s];
      for (uint32_t i = lane; i < ((sn + 63u) & ~63u); i += 64) {
        bool valid = (i < sn);
        uint64_t kk = valid ? sg[i] : 0ull;
        wave_append(kk, valid && ((uint32_t)(kk >> 32) >= thresh), &res[3], sbuf, lane);
      }
    }
    __syncthreads();
  }

  uint64_t e0 = sbuf[tid], e1 = sbuf[tid + 1024];
  bitonic2048_reg(e0, e1, sbuf, tid, lane);

  if (tid < KTOP) {
    uint64_t kk = sbuf[tid];
    float score; uint32_t idx;
    if (kk == 0ull) { score = 0.0f; idx = 0u; }
    else {
      idx = ~(uint32_t)kk;
      float v = unflipbits((uint32_t)(kk >> 32));
      score = 1.0f / (1.0f + expf(-v));
    }
    s1_scores[bc * 512 + tid] = score;
    s1_inds  [bc * 512 + tid] = idx;
  }
}

// ============ Kernel 3: per-batch top-500 of 1500 + gather + emit ============
__global__ __launch_bounds__(1024) void k_final(
    const float* __restrict__ s1_scores, const uint32_t* __restrict__ s1_inds,
    const float* __restrict__ cen_offset, const float* __restrict__ direction,
    const float* __restrict__ z_coor, const float* __restrict__ dimf,
    float* __restrict__ out)
{
  __shared__ uint64_t sbuf[2048];
  const int b = blockIdx.x, tid = threadIdx.x, lane = tid & 63;

  uint64_t e0 = 0, e1 = 0;
  if (tid < Cn * KTOP) {
    int c = tid / KTOP, r = tid % KTOP;
    float s = s1_scores[(b * Cn + c) * 512 + r];
    e0 = ((uint64_t)flipbits(s) << 32) | (uint32_t)(~(uint32_t)tid);
  }
  {
    int t1 = tid + 1024;
    if (t1 < Cn * KTOP) {
      int c = t1 / KTOP, r = t1 % KTOP;
      float s = s1_scores[(b * Cn + c) * 512 + r];
      e1 = ((uint64_t)flipbits(s) << 32) | (uint32_t)(~(uint32_t)t1);
    }
  }
  bitonic2048_reg(e0, e1, sbuf, tid, lane);

  const float* co = cen_offset + (size_t)b * 2 * HWp;
  const float* di = direction  + (size_t)b * 2 * HWp;
  const float* zc = z_coor     + (size_t)b * HWp;
  const float* dm = dimf       + (size_t)b * 3 * HWp;

  // qf-major mapping: wave-uniform switch
  for (int t = tid; t < KTOP * 10; t += 1024) {
    int qf = t / KTOP, item = t - qf * KTOP;
    uint64_t kk = sbuf[item];
    uint32_t pos = ~(uint32_t)kk;
    int c = (int)(pos / KTOP), r = (int)(pos - (uint32_t)c * KTOP);
    int bcx = b * Cn + c;
    uint32_t ind = s1_inds[bcx * 512 + r];
    float val;
    switch (qf) {
      case 0: val = s1_scores[bcx * 512 + r]; break;
      case 1: val = (float)(ind & (Wd - 1)) + co[ind]; break;
      case 2: val = (float)(ind >> 9) + co[HWp + ind]; break;
      case 3: val = zc[ind]; break;
      case 4: val = dm[ind]; break;
      case 5: val = dm[HWp + ind]; break;
      case 6: val = dm[2 * HWp + ind]; break;
      case 7: val = di[ind]; break;
      case 8: val = di[HWp + ind]; break;
      default: val = (float)c; break;
    }
    out[((size_t)b * KTOP + item) * 10 + qf] = val;
  }
}

extern "C" void kernel_launch(void* const* d_in, const int* in_sizes, int n_in,
                              void* d_out, int out_size, void* d_ws, size_t ws_size,
                              hipStream_t stream)
{
  const float* hm         = (const float*)d_in[0];
  const float* cen_offset = (const float*)d_in[1];
  const float* direction  = (const float*)d_in[2];
  const float* z_coor     = (const float*)d_in[3];
  const float* dimf       = (const float*)d_in[4];
  float* out = (float*)d_out;

  // ws: cnt[NMAP*SEGS]u32 (pad 16K) | s1_sc | s1_id | cand[NMAP*SEGS*capw]u64
  char* ws = (char*)d_ws;
  uint32_t* cnt   = (uint32_t*)ws;
  float*    s1_sc = (float*)(ws + 16384);
  uint32_t* s1_id = (uint32_t*)(ws + 16384 + (size_t)NMAP * 512 * 4);
  size_t fixed    = 16384 + (size_t)NMAP * 512 * 4 * 2;
  uint64_t* cand  = (uint64_t*)(ws + fixed);

  int capw = CAPW_MAX;
  size_t need = fixed + (size_t)NMAP * SEGS * (size_t)capw * 8;
  if (ws_size < need) {
    size_t avail = (ws_size > fixed) ? (ws_size - fixed) : 0;
    capw = (int)(avail / ((size_t)NMAP * SEGS * 8));
    if (capw > CAPW_MAX) capw = CAPW_MAX;
    if (capw < 128) capw = 128;   // last-ditch; expected never hit
  }

  k_nms<<<NMAP * SLICES, 256, 0, stream>>>(hm, cand, cnt, capw);
  k_select<<<NMAP, 1024, 0, stream>>>(cand, cnt, capw, s1_sc, s1_id);
  k_final<<<Bn, 1024, 0, stream>>>(s1_sc, s1_id, cen_offset, direction, z_coor, dimf, out);
}

// Round 5
// 69.783 us; speedup vs baseline: 15.5318x; 1.2960x over previous
//
#include <hip/hip_runtime.h>
#include <math.h>
#include <float.h>

#define Hd 512
#define Wd 512
#define HWp (Hd*Wd)
#define Bn 16
#define Cn 3
#define NMAP (Bn*Cn)
#define KTOP 500
#define SLICES 32
#define ROWS_SL 16          // rows per slice (block)
#define WPB 4               // waves per block
#define ROWS_W 4            // rows per wave
#define SEGS (SLICES*WPB)   // 128 private segments per map
#define CAPW_MAX 512        // worst-case (stride-2) peaks in a 4-row band
#define SPW (SEGS/16)       // segments per wave in k_select = 8

__device__ __forceinline__ uint32_t flipbits(float v){
  uint32_t u = __float_as_uint(v);
  return u ^ (0x80000000u | (uint32_t)(-(int32_t)(u>>31)));
}
__device__ __forceinline__ float unflipbits(uint32_t f){
  uint32_t u = f ^ ((f>>31)? 0x80000000u : 0xFFFFFFFFu);
  return __uint_as_float(u);
}

// ============ Kernel 1: NMS, wave-per-4-rows, ballot-based compaction ============
__global__ __launch_bounds__(256) void k_nms(
    const float* __restrict__ hm, uint64_t* __restrict__ cand,
    uint32_t* __restrict__ cnt, int capw)
{
  const int bc    = blockIdx.x / SLICES;
  const int slice = blockIdx.x % SLICES;
  const int tid   = threadIdx.x;
  const int lane  = tid & 63;
  const int w     = tid >> 6;
  const float* map = hm + (size_t)bc * HWp;
  const int segid = (bc*SLICES + slice)*WPB + w;
  uint64_t* seg = cand + (size_t)segid * (size_t)capw;
  const int y0 = slice*ROWS_SL + w*ROWS_W;
  const int xb = lane*8;
  const uint64_t lt = (1ull << lane) - 1ull;
  const float4 NEG4 = make_float4(-INFINITY,-INFINITY,-INFINITY,-INFINITY);

  float4 p0, p1, c0, c1;
  if (y0 > 0) {
    const float* rp = map + (size_t)(y0-1)*Wd + xb;
    p0 = *(const float4*)rp; p1 = *(const float4*)(rp+4);
  } else { p0 = NEG4; p1 = NEG4; }
  {
    const float* rp = map + (size_t)y0*Wd + xb;
    c0 = *(const float4*)rp; c1 = *(const float4*)(rp+4);
  }

  uint32_t my_off = 0;
  #pragma unroll
  for (int r = 0; r < ROWS_W; ++r) {
    const int y = y0 + r, yn = y + 1;
    float4 n0, n1;
    if (yn < Hd) {
      const float* rp = map + (size_t)yn*Wd + xb;
      n0 = *(const float4*)rp; n1 = *(const float4*)(rp+4);
    } else { n0 = NEG4; n1 = NEG4; }

    float vm0 = fmaxf(fmaxf(p0.x,c0.x),n0.x);
    float vm1 = fmaxf(fmaxf(p0.y,c0.y),n0.y);
    float vm2 = fmaxf(fmaxf(p0.z,c0.z),n0.z);
    float vm3 = fmaxf(fmaxf(p0.w,c0.w),n0.w);
    float vm4 = fmaxf(fmaxf(p1.x,c1.x),n1.x);
    float vm5 = fmaxf(fmaxf(p1.y,c1.y),n1.y);
    float vm6 = fmaxf(fmaxf(p1.z,c1.z),n1.z);
    float vm7 = fmaxf(fmaxf(p1.w,c1.w),n1.w);
    float vmL = __shfl_up(vm7, 1);   if (lane == 0)  vmL = -INFINITY;
    float vmR = __shfl_down(vm0, 1); if (lane == 63) vmR = -INFINITY;

    float m0 = fmaxf(vmL, fmaxf(vm0, vm1));
    float m1 = fmaxf(vm0, fmaxf(vm1, vm2));
    float m2 = fmaxf(vm1, fmaxf(vm2, vm3));
    float m3 = fmaxf(vm2, fmaxf(vm3, vm4));
    float m4 = fmaxf(vm3, fmaxf(vm4, vm5));
    float m5 = fmaxf(vm4, fmaxf(vm5, vm6));
    float m6 = fmaxf(vm5, fmaxf(vm6, vm7));
    float m7 = fmaxf(vm6, fmaxf(vm7, vmR));

    uint32_t pk = 0;
    if (c0.x >= m0) pk |= 1u;
    if (c0.y >= m1) pk |= 2u;
    if (c0.z >= m2) pk |= 4u;
    if (c0.w >= m3) pk |= 8u;
    if (c1.x >= m4) pk |= 16u;
    if (c1.y >= m5) pk |= 32u;
    if (c1.z >= m6) pk |= 64u;
    if (c1.w >= m7) pk |= 128u;

    float cv[8]; cv[0]=c0.x; cv[1]=c0.y; cv[2]=c0.z; cv[3]=c0.w;
    cv[4]=c1.x; cv[5]=c1.y; cv[6]=c1.z; cv[7]=c1.w;
    const uint32_t ib = (uint32_t)(y*Wd + xb);
    // ballot-based slot assignment: no shfl chain; order within segment irrelevant
    #pragma unroll
    for (int i = 0; i < 8; ++i) {
      unsigned long long bi = __ballot((pk >> i) & 1u);
      if ((pk >> i) & 1u) {
        uint32_t p = my_off + (uint32_t)__popcll(bi & lt);
        if (p < (uint32_t)capw)
          seg[p] = ((uint64_t)flipbits(cv[i]) << 32) | (uint32_t)(~(ib + (uint32_t)i));
      }
      my_off += (uint32_t)__popcll(bi);   // wave-uniform
    }
    p0 = c0; p1 = c1; c0 = n0; c1 = n1;
  }
  if (lane == 0) cnt[segid] = (my_off < (uint32_t)capw) ? my_off : (uint32_t)capw;
}

// ============ shfl suffix-scan threshold finder ============
__device__ __forceinline__ void findThreshold2(
    const uint32_t* hist, uint32_t target, int tid, int lane, int wid,
    uint32_t* wtot, uint32_t* res)
{
  uint32_t s = hist[4*tid] + hist[4*tid+1] + hist[4*tid+2] + hist[4*tid+3];
  uint32_t v = s;
  #pragma unroll
  for (int d = 1; d < 64; d <<= 1) { uint32_t u = __shfl_down(v, d); if (lane + d < 64) v += u; }
  if (lane == 0) wtot[wid] = v;
  __syncthreads();
  uint32_t above = 0;
  for (int ww = wid + 1; ww < 16; ++ww) above += wtot[ww];
  uint32_t gsuf = v + above;
  if (gsuf >= target && (gsuf - s) < target) {
    uint32_t cum = gsuf - s;
    for (int b = 4*tid + 3; b >= 4*tid; --b) {
      cum += hist[b];
      if (cum >= target) { res[0]=(uint32_t)b; res[1]=target-(cum-hist[b]); res[2]=cum; break; }
    }
  }
  __syncthreads();
}

// ============ register bitonic sort of 2048 keys (desc), 1024 threads ============
__device__ __forceinline__ uint64_t cexch(uint64_t mine, uint64_t part, bool wantMax) {
  uint64_t mx = mine > part ? mine : part;
  uint64_t mn = mine > part ? part : mine;
  return wantMax ? mx : mn;
}

__device__ void bitonic2048_reg(uint64_t& e0, uint64_t& e1, uint64_t* sbuf, int tid, int lane)
{
  const int i1 = tid + 1024;
  for (int k = 2; k <= 2048; k <<= 1) {
    for (int j = k >> 1; j > 0; j >>= 1) {
      if (j >= 1024) {
        uint64_t mx = e0 > e1 ? e0 : e1;
        uint64_t mn = e0 > e1 ? e1 : e0;
        e0 = mx; e1 = mn;
      } else if (j >= 64) {
        __syncthreads();
        sbuf[tid] = e0; sbuf[i1] = e1;
        __syncthreads();
        uint64_t q0 = sbuf[tid ^ j];
        uint64_t q1 = sbuf[i1 ^ j];
        bool amS = ((tid & j) == 0);
        e0 = cexch(e0, q0, ((tid & k) == 0) == amS);
        e1 = cexch(e1, q1, ((i1  & k) == 0) == amS);
      } else {
        uint64_t q0 = __shfl_xor((unsigned long long)e0, j);
        uint64_t q1 = __shfl_xor((unsigned long long)e1, j);
        bool amS = ((lane & j) == 0);
        e0 = cexch(e0, q0, ((tid & k) == 0) == amS);
        e1 = cexch(e1, q1, ((i1  & k) == 0) == amS);
      }
    }
  }
  __syncthreads();
  sbuf[tid] = e0; sbuf[i1] = e1;
  __syncthreads();
}

__device__ __forceinline__ void wave_append(uint64_t kk, bool keep, uint32_t* ctr,
                                            uint64_t* sbuf, int lane)
{
  unsigned long long mk = __ballot(keep);
  if (!mk) return;
  uint32_t tot = (uint32_t)__popcll(mk);
  uint32_t b = 0;
  if (lane == 0) b = atomicAdd(ctr, tot);
  b = __shfl(b, 0);
  if (keep) {
    uint32_t p = b + (uint32_t)__popcll(mk & ((1ull << lane) - 1ull));
    if (p < 2048) sbuf[p] = kk;
  }
}

// ============ Kernel 2: per-(b,c) top-500, 8-way MLP scans ============
__global__ __launch_bounds__(1024) void k_select(
    const uint64_t* __restrict__ cand, const uint32_t* __restrict__ cnt, int capw,
    float* __restrict__ s1_scores, uint32_t* __restrict__ s1_inds)
{
  __shared__ uint32_t hist[4096];
  __shared__ uint64_t sbuf[2048];
  __shared__ uint32_t segn[SEGS];
  __shared__ uint32_t wtot[16];
  __shared__ uint32_t res[4];     // 0:bin 1:krem 2:M 3:append counter
  __shared__ uint32_t sh_n;

  const int bc = blockIdx.x, tid = threadIdx.x;
  const int lane = tid & 63, wid = tid >> 6;
  const uint64_t* base = cand + (size_t)bc * SEGS * (size_t)capw;

  if (tid < SEGS) segn[tid] = min(cnt[bc*SEGS + tid], (uint32_t)capw);
  for (int i = tid; i < 4096; i += 1024) hist[i] = 0;
  sbuf[tid] = 0; sbuf[tid + 1024] = 0;
  if (tid == 0) res[3] = 0;
  __syncthreads();

  if (wid == 0) {
    uint32_t v = segn[lane] + segn[lane + 64];
    #pragma unroll
    for (int d = 1; d < 64; d <<= 1) { uint32_t u = __shfl_down(v, d); if (lane + d < 64) v += u; }
    if (lane == 0) sh_n = v;
  }
  __syncthreads();
  const uint32_t n = sh_n;

  // this wave's 8 segments (contiguous for L2/L3 locality)
  uint32_t sn[SPW]; const uint64_t* sg[SPW]; uint32_t mx = 0;
  #pragma unroll
  for (int t = 0; t < SPW; ++t) {
    int s = wid * SPW + t;
    sn[t] = segn[s];
    sg[t] = base + (size_t)s * capw;
    mx = max(mx, sn[t]);
  }

  if (n <= 2048) {
    #pragma unroll 1
    for (uint32_t i = lane; i < mx; i += 64) {
      uint64_t kk[SPW];
      #pragma unroll
      for (int t = 0; t < SPW; ++t) kk[t] = (i < sn[t]) ? sg[t][i] : 0ull;
      #pragma unroll
      for (int t = 0; t < SPW; ++t) wave_append(kk[t], i < sn[t], &res[3], sbuf, lane);
    }
    __syncthreads();
  } else {
    // pass A: histogram of top-12 bits, 8 loads in flight
    #pragma unroll 1
    for (uint32_t i = lane; i < mx; i += 64) {
      uint64_t kk[SPW];
      #pragma unroll
      for (int t = 0; t < SPW; ++t) kk[t] = (i < sn[t]) ? sg[t][i] : 0ull;
      #pragma unroll
      for (int t = 0; t < SPW; ++t) if (i < sn[t]) atomicAdd(&hist[(uint32_t)(kk[t] >> 52)], 1u);
    }
    __syncthreads();
    findThreshold2(hist, KTOP, tid, lane, wid, wtot, res);
    const uint32_t T1 = res[0], krem = res[1], M = res[2];
    __syncthreads();
    uint32_t thresh;
    if (M <= 2048) {
      thresh = T1 << 20;
    } else {
      for (int i = tid; i < 4096; i += 1024) hist[i] = 0;
      __syncthreads();
      #pragma unroll 1
      for (uint32_t i = lane; i < mx; i += 64) {
        uint64_t kk[SPW];
        #pragma unroll
        for (int t = 0; t < SPW; ++t) kk[t] = (i < sn[t]) ? sg[t][i] : 0ull;
        #pragma unroll
        for (int t = 0; t < SPW; ++t) {
          uint32_t f = (uint32_t)(kk[t] >> 32);
          if (i < sn[t] && (f >> 20) == T1) atomicAdd(&hist[(f >> 8) & 0xFFFu], 1u);
        }
      }
      __syncthreads();
      findThreshold2(hist, krem, tid, lane, wid, wtot, res);
      thresh = (T1 << 20) | (res[0] << 8);
      __syncthreads();
    }
    // pass B: compact survivors, 8 loads in flight
    #pragma unroll 1
    for (uint32_t i = lane; i < mx; i += 64) {
      uint64_t kk[SPW];
      #pragma unroll
      for (int t = 0; t < SPW; ++t) kk[t] = (i < sn[t]) ? sg[t][i] : 0ull;
      #pragma unroll
      for (int t = 0; t < SPW; ++t)
        wave_append(kk[t], (i < sn[t]) && ((uint32_t)(kk[t] >> 32) >= thresh), &res[3], sbuf, lane);
    }
    __syncthreads();
  }

  uint64_t e0 = sbuf[tid], e1 = sbuf[tid + 1024];
  bitonic2048_reg(e0, e1, sbuf, tid, lane);

  if (tid < KTOP) {
    uint64_t kk = sbuf[tid];
    float score; uint32_t idx;
    if (kk == 0ull) { score = 0.0f; idx = 0u; }
    else {
      idx = ~(uint32_t)kk;
      float v = unflipbits((uint32_t)(kk >> 32));
      score = 1.0f / (1.0f + expf(-v));
    }
    s1_scores[bc * 512 + tid] = score;
    s1_inds  [bc * 512 + tid] = idx;
  }
}

// ============ Kernel 3: merge-rank (no sort) + gather + emit ============
__global__ __launch_bounds__(1024) void k_final(
    const float* __restrict__ s1_scores, const uint32_t* __restrict__ s1_inds,
    const float* __restrict__ cen_offset, const float* __restrict__ direction,
    const float* __restrict__ z_coor, const float* __restrict__ dimf,
    float* __restrict__ out)
{
  __shared__ float ssc[Cn][KTOP];
  const int b = blockIdx.x, tid = threadIdx.x;

  for (int i = tid; i < Cn * KTOP; i += 1024) {
    int c = i / KTOP, r = i - c * KTOP;
    ssc[c][r] = s1_scores[(b * Cn + c) * 512 + r];
  }
  __syncthreads();

  const float* co = cen_offset + (size_t)b * 2 * HWp;
  const float* di = direction  + (size_t)b * 2 * HWp;
  const float* zc = z_coor     + (size_t)b * HWp;
  const float* dm = dimf       + (size_t)b * 3 * HWp;

  for (int i = tid; i < Cn * KTOP; i += 1024) {
    const int c = i / KTOP, r = i - c * KTOP;
    const uint64_t mykey = ((uint64_t)flipbits(ssc[c][r]) << 32) | (uint32_t)(~(uint32_t)i);
    int rank = r;
    #pragma unroll
    for (int cd = 1; cd < Cn; ++cd) {
      const int cc = (c + cd) % Cn;      // the other two classes
      int lo = 0, hi = KTOP;
      while (lo < hi) {
        int mid = (lo + hi) >> 1;
        uint64_t k2 = ((uint64_t)flipbits(ssc[cc][mid]) << 32)
                    | (uint32_t)(~(uint32_t)(cc * KTOP + mid));
        if (k2 > mykey) lo = mid + 1; else hi = mid;
      }
      rank += lo;
    }
    if (rank < KTOP) {
      const int bcx = b * Cn + c;
      const uint32_t ind = s1_inds[bcx * 512 + r];
      float o[10];
      o[0] = ssc[c][r];
      o[1] = (float)(ind & (Wd - 1)) + co[ind];
      o[2] = (float)(ind >> 9) + co[HWp + ind];
      o[3] = zc[ind];
      o[4] = dm[ind];
      o[5] = dm[HWp + ind];
      o[6] = dm[2 * HWp + ind];
      o[7] = di[ind];
      o[8] = di[HWp + ind];
      o[9] = (float)c;
      float* op = out + ((size_t)b * KTOP + rank) * 10;
      #pragma unroll
      for (int q = 0; q < 10; ++q) op[q] = o[q];
    }
  }
}

extern "C" void kernel_launch(void* const* d_in, const int* in_sizes, int n_in,
                              void* d_out, int out_size, void* d_ws, size_t ws_size,
                              hipStream_t stream)
{
  const float* hm         = (const float*)d_in[0];
  const float* cen_offset = (const float*)d_in[1];
  const float* direction  = (const float*)d_in[2];
  const float* z_coor     = (const float*)d_in[3];
  const float* dimf       = (const float*)d_in[4];
  float* out = (float*)d_out;

  // ws: cnt[NMAP*SEGS]u32 (pad 32K) | s1_sc | s1_id | cand[NMAP*SEGS*capw]u64
  char* ws = (char*)d_ws;
  uint32_t* cnt   = (uint32_t*)ws;
  float*    s1_sc = (float*)(ws + 32768);
  uint32_t* s1_id = (uint32_t*)(ws + 32768 + (size_t)NMAP * 512 * 4);
  size_t fixed    = 32768 + (size_t)NMAP * 512 * 4 * 2;
  uint64_t* cand  = (uint64_t*)(ws + fixed);

  int capw = CAPW_MAX;
  size_t need = fixed + (size_t)NMAP * SEGS * (size_t)capw * 8;
  if (ws_size < need) {
    size_t avail = (ws_size > fixed) ? (ws_size - fixed) : 0;
    capw = (int)(avail / ((size_t)NMAP * SEGS * 8));
    if (capw > CAPW_MAX) capw = CAPW_MAX;
    if (capw < 64) capw = 64;   // last-ditch; expected never hit
  }

  k_nms<<<NMAP * SLICES, 256, 0, stream>>>(hm, cand, cnt, capw);
  k_select<<<NMAP, 1024, 0, stream>>>(cand, cnt, capw, s1_sc, s1_id);
  k_final<<<Bn, 1024, 0, stream>>>(s1_sc, s1_id, cen_offset, direction, z_coor, dimf, out);
}